// Round 1
// baseline (672.570 us; speedup 1.0000x reference)
//
#include <hip/hip_runtime.h>

#define VOCAB   32000
#define D       128
#define NNODES  50000
#define NEDGES  600000

// ---------------------------------------------------------------------------
// Table MLP: out[r][:] = relu(emb[r][:] @ w + b)  for r in [0, rows)
// w (128x128 f32 = 64KB) cached in LDS. 256 threads = 4 rows in flight,
// 64 lanes per row, each lane computes columns (lane, lane+64) so the two
// w reads per k merge into ds_read2_b32; x read is a wave broadcast.
// ---------------------------------------------------------------------------
__global__ __launch_bounds__(256) void mlp_table_kernel(
    const float* __restrict__ emb,
    const float* __restrict__ w,
    const float* __restrict__ b,
    float* __restrict__ outt,
    int rows)
{
    __shared__ float w_lds[D * D];
    __shared__ float x_lds[4][D];
    __shared__ float b_lds[D];

    for (int i = threadIdx.x; i < D * D; i += 256) w_lds[i] = w[i];
    if (threadIdx.x < D) b_lds[threadIdx.x] = b[threadIdx.x];
    __syncthreads();

    const int sub  = threadIdx.x >> 6;   // row slot 0..3
    const int lane = threadIdx.x & 63;
    const int c0 = lane, c1 = lane + 64;

    const int rows_per_iter = gridDim.x * 4;
    const int iters = (rows + rows_per_iter - 1) / rows_per_iter;

    for (int it = 0; it < iters; ++it) {
        const int row = (it * gridDim.x + blockIdx.x) * 4 + sub;
        const bool valid = row < rows;
        __syncthreads();   // protect x_lds from previous iteration's readers
        if (valid) {
            float2 v = ((const float2*)(emb + (size_t)row * D))[lane];
            ((float2*)x_lds[sub])[lane] = v;
        }
        __syncthreads();
        if (valid) {
            float acc0 = b_lds[c0], acc1 = b_lds[c1];
            #pragma unroll
            for (int k = 0; k < D; k += 4) {
                float4 xv = *(const float4*)&x_lds[sub][k];
                acc0 += xv.x * w_lds[(k + 0) * D + c0];
                acc1 += xv.x * w_lds[(k + 0) * D + c1];
                acc0 += xv.y * w_lds[(k + 1) * D + c0];
                acc1 += xv.y * w_lds[(k + 1) * D + c1];
                acc0 += xv.z * w_lds[(k + 2) * D + c0];
                acc1 += xv.z * w_lds[(k + 2) * D + c1];
                acc0 += xv.w * w_lds[(k + 3) * D + c0];
                acc1 += xv.w * w_lds[(k + 3) * D + c1];
            }
            float* o = outt + (size_t)row * D;
            o[c0] = fmaxf(acc0, 0.f);
            o[c1] = fmaxf(acc1, 0.f);
        }
    }
}

// ---------------------------------------------------------------------------
// Edge kernel: one wave per edge.
//   msg = table1[node_tokens[src[e]]] * table2[edge_tokens[e]]
//   atomicAdd into out[dst[e]]
// Each lane handles 2 consecutive floats (float2 gather, 2 f32 atomics).
// ---------------------------------------------------------------------------
__global__ __launch_bounds__(256) void edge_kernel(
    const float* __restrict__ t1,
    const float* __restrict__ t2,
    const int* __restrict__ node_tokens,
    const int* __restrict__ edge_tokens,
    const int* __restrict__ srcv,
    const int* __restrict__ dstv,
    float* __restrict__ outp,
    int n_edges)
{
    int wid = (blockIdx.x * 256 + threadIdx.x) >> 6;
    if (wid >= n_edges) return;
    const int e = __builtin_amdgcn_readfirstlane(wid);  // wave-uniform -> SGPR
    const int lane = threadIdx.x & 63;

    const int s  = srcv[e];
    const int dn = dstv[e];
    const int te = edge_tokens[e];
    const int tn = node_tokens[s];

    float2 a  = ((const float2*)(t1 + (size_t)tn * D))[lane];
    float2 bb = ((const float2*)(t2 + (size_t)te * D))[lane];

    float* o = outp + (size_t)dn * D + 2 * lane;
    atomicAdd(o,     a.x * bb.x);
    atomicAdd(o + 1, a.y * bb.y);
}

extern "C" void kernel_launch(void* const* d_in, const int* in_sizes, int n_in,
                              void* d_out, int out_size, void* d_ws, size_t ws_size,
                              hipStream_t stream) {
    const float* emb = (const float*)d_in[0];
    const float* w1  = (const float*)d_in[1];
    const float* b1  = (const float*)d_in[2];
    const float* w2  = (const float*)d_in[3];
    const float* b2  = (const float*)d_in[4];
    const int* node_tokens = (const int*)d_in[5];
    const int* edge_tokens = (const int*)d_in[6];
    const int* src = (const int*)d_in[7];
    const int* dst = (const int*)d_in[8];
    float* out = (float*)d_out;

    // workspace: two vocab-sized activation tables (2 * 16.38 MB)
    float* t1 = (float*)d_ws;
    float* t2 = t1 + (size_t)VOCAB * D;

    // out is poisoned with 0xAA before every timed launch -> zero it
    hipMemsetAsync(d_out, 0, (size_t)out_size * sizeof(float), stream);

    mlp_table_kernel<<<512, 256, 0, stream>>>(emb, w1, b1, t1, VOCAB);
    mlp_table_kernel<<<512, 256, 0, stream>>>(emb, w2, b2, t2, VOCAB);

    const int n_waves  = NEDGES;           // 1 wave per edge
    const int n_blocks = n_waves / 4;      // 4 waves per 256-thread block
    edge_kernel<<<n_blocks, 256, 0, stream>>>(t1, t2, node_tokens, edge_tokens,
                                              src, dst, out, NEDGES);
}